// Round 8
// baseline (94.521 us; speedup 1.0000x reference)
//
#include <hip/hip_runtime.h>
#include <math.h>

#define CB_M 64      // codewords
#define CB_D 16      // vector dim
#define HARD 5.0f
#define LOG2E 1.44269504088896340736f

typedef __attribute__((ext_vector_type(8))) short bf16x8;  // 8 bf16 = 4 VGPRs
typedef __attribute__((ext_vector_type(4))) float f32x4;
typedef __attribute__((ext_vector_type(4))) int   i32x4;

#if __has_builtin(__builtin_amdgcn_exp2f)
#define EXP2F(x) __builtin_amdgcn_exp2f(x)
#else
#define EXP2F(x) exp2f(x)
#endif

#if __has_builtin(__builtin_amdgcn_rcpf)
#define RCPF(x) __builtin_amdgcn_rcpf(x)
#else
#define RCPF(x) (1.0f / (x))
#endif

__device__ __forceinline__ ushort f2bf_rne(float f) {
    unsigned u = __float_as_uint(f);
    u += 0x7fffu + ((u >> 16) & 1u);       // RNE (prep path only)
    return (ushort)(u >> 16);
}
__device__ __forceinline__ float bf2f(ushort h) {
    return __uint_as_float(((unsigned)h) << 16);
}
// pack [bf16(a) : bf16(b)] into one dword (a = high half), TRUNCATING
__device__ __forceinline__ int pk(float a, float b) {
    return (int)__builtin_amdgcn_perm(__float_as_uint(a), __float_as_uint(b), 0x07060302u);
}
// half-ulp bump so a following truncation rounds to nearest
__device__ __forceinline__ float rnd(float a) {
    return __uint_as_float(__float_as_uint(a) + 0x8000u);
}
// truncate float to bf16 value (exact residual split)
__device__ __forceinline__ float hi_trunc(float a) {
    return __uint_as_float(__float_as_uint(a) & 0xffff0000u);
}

// ws layout (bytes):
//   0    : bias  f32[64]        -H*log2e*||r_m||^2
//   256  : rs_hi u16[64][16]    bf16 hi of (2H*log2e)*r
//   2304 : rs_lo u16[64][16]    residual
//   4352 : rzT_hi u16[16][64]   r^T hi
//   6400 : rzT_lo u16[16][64]   residual
__global__ void stq_prep(const float* __restrict__ ref, char* __restrict__ ws) {
    float*  bias   = (float*)(ws);
    ushort* rs_hi  = (ushort*)(ws + 256);
    ushort* rs_lo  = (ushort*)(ws + 2304);
    ushort* rzT_hi = (ushort*)(ws + 4352);
    ushort* rzT_lo = (ushort*)(ws + 6400);

    int m = threadIdx.x;
    if (m >= CB_M) return;
    float r[CB_D];
    float r2 = 0.0f;
#pragma unroll
    for (int j = 0; j < CB_D; ++j) { r[j] = ref[m * CB_D + j]; r2 += r[j] * r[j]; }
    bias[m] = -(HARD * LOG2E) * r2;
    const float s = 2.0f * HARD * LOG2E;
#pragma unroll
    for (int j = 0; j < CB_D; ++j) {
        float v = s * r[j];
        ushort h = f2bf_rne(v);
        rs_hi[m * CB_D + j] = h;
        rs_lo[m * CB_D + j] = f2bf_rne(v - bf2f(h));
        ushort zh = f2bf_rne(r[j]);
        rzT_hi[j * CB_M + m] = zh;
        rzT_lo[j * CB_M + m] = f2bf_rne(r[j] - bf2f(zh));
    }
}

// Non-persistent main: each wave does exactly TILES_PW=2 consecutive 16-row
// tiles. No LDS, no barrier. Transposed-S + codeword-permutation trick:
//   S^T = Rperm @ Xsplit   (cw(t,m)=32(t>>1)+8(m>>2)+4(t&1)+(m&3) makes the
//   softmaxed C-layout registers exactly the Z-GEMM's A-operand layout)
#define TILES_PW 2
__global__ __launch_bounds__(256, 4) void stq_main(const float* __restrict__ x,
                                                   const char* __restrict__ ws,
                                                   float* __restrict__ out,
                                                   int ntiles) {
    const float*  bias   = (const float*)(ws);
    const ushort* rs_hi  = (const ushort*)(ws + 256);
    const ushort* rs_lo  = (const ushort*)(ws + 2304);
    const ushort* rzT_hi = (const ushort*)(ws + 4352);
    const ushort* rzT_lo = (const ushort*)(ws + 6400);

    const int lane = threadIdx.x & 63;
    const int wid  = threadIdx.x >> 6;
    const int i = lane & 15;        // fragment n-index (vector row / Z dim)
    const int c = lane >> 4;        // k-octet quad

    const int wave_id = blockIdx.x * 4 + wid;
    const int t0 = wave_id * TILES_PW;
    if (t0 >= ntiles) return;

    // ---- issue both tiles' X loads first (independent, hide HBM latency)
    f32x4 xa0, xb0, xa1, xb1;
    {
        const float* xp0 = x + ((size_t)t0 * 16 + i) * CB_D + (c & 1) * 8;
        xa0 = *(const f32x4*)xp0;
        xb0 = *(const f32x4*)(xp0 + 4);
        const float* xp1 = xp0 + 16 * CB_D;
        xa1 = *(const f32x4*)xp1;
        xb1 = *(const f32x4*)(xp1 + 4);
    }

    // ---- codebook fragments (L1/L2-hot 8.5 KB region) ----
    bf16x8 A1[4], A2[4];
    f32x4  cinit[4];
    bf16x8 zfrag;
#pragma unroll
    for (int j = 0; j < 8; ++j) zfrag[j] = 0;
#pragma unroll
    for (int t = 0; t < 4; ++t) {
        const int cwa = 32 * (t >> 1) + 8 * (i >> 2) + 4 * (t & 1) + (i & 3);
        const ushort* src = (c < 2) ? (rs_hi + cwa * CB_D) : (rs_lo + cwa * CB_D);
        A1[t] = *(const bf16x8*)(src + (c & 1) * 8);
        A2[t] = (c < 2) ? A1[t] : zfrag;
#pragma unroll
        for (int r = 0; r < 4; ++r)
            cinit[t][r] = bias[32 * (t >> 1) + 8 * c + 4 * (t & 1) + r];
    }
    bf16x8 BzH0 = *(const bf16x8*)(rzT_hi + i * CB_M + c * 8);
    bf16x8 BzH1 = *(const bf16x8*)(rzT_hi + i * CB_M + 32 + c * 8);
    bf16x8 BzL0 = *(const bf16x8*)(rzT_lo + i * CB_M + c * 8);
    bf16x8 BzL1 = *(const bf16x8*)(rzT_lo + i * CB_M + 32 + c * 8);

#pragma unroll
    for (int q = 0; q < TILES_PW; ++q) {
        const int tile = t0 + q;
        if (tile >= ntiles) break;
        f32x4 xa = q ? xa1 : xa0;
        f32x4 xb = q ? xb1 : xb0;

        // ---- B fragments: B1 = x_hi (trunc), B2 = rounded residual ----
        i32x4 B1i, B2i;
        B1i.x = pk(xa.y, xa.x); B1i.y = pk(xa.w, xa.z);
        B1i.z = pk(xb.y, xb.x); B1i.w = pk(xb.w, xb.z);
        float l0 = xa.x - hi_trunc(xa.x), l1 = xa.y - hi_trunc(xa.y);
        float l2 = xa.z - hi_trunc(xa.z), l3 = xa.w - hi_trunc(xa.w);
        float l4 = xb.x - hi_trunc(xb.x), l5 = xb.y - hi_trunc(xb.y);
        float l6 = xb.z - hi_trunc(xb.z), l7 = xb.w - hi_trunc(xb.w);
        B2i.x = pk(rnd(l1), rnd(l0)); B2i.y = pk(rnd(l3), rnd(l2));
        B2i.z = pk(rnd(l5), rnd(l4)); B2i.w = pk(rnd(l7), rnd(l6));
        bf16x8 B1 = __builtin_bit_cast(bf16x8, B1i);
        bf16x8 B2 = __builtin_bit_cast(bf16x8, B2i);

        // ---- S^T GEMM: acc[t][r] = logit[cw 32(t>>1)+8c+4(t&1)+r][row i]
        f32x4 acc[4];
#pragma unroll
        for (int t = 0; t < 4; ++t) {
            acc[t] = __builtin_amdgcn_mfma_f32_16x16x32_bf16(A1[t], B1, cinit[t], 0, 0, 0);
            acc[t] = __builtin_amdgcn_mfma_f32_16x16x32_bf16(A2[t], B2, acc[t], 0, 0, 0);
        }

        // ---- row softmax: lanes {i,16+i,32+i,48+i} hold row i's 64 logits
        float lmax = acc[0][0];
#pragma unroll
        for (int t = 0; t < 4; ++t)
#pragma unroll
            for (int r = 0; r < 4; ++r) lmax = fmaxf(lmax, acc[t][r]);
        lmax = fmaxf(lmax, __shfl_xor(lmax, 16, 64));
        lmax = fmaxf(lmax, __shfl_xor(lmax, 32, 64));

        float e[4][4];
        float lsum = 0.0f;
#pragma unroll
        for (int t = 0; t < 4; ++t)
#pragma unroll
            for (int r = 0; r < 4; ++r) { e[t][r] = EXP2F(acc[t][r] - lmax); lsum += e[t][r]; }
        lsum += __shfl_xor(lsum, 16, 64);
        lsum += __shfl_xor(lsum, 32, 64);
        const float inv = RCPF(lsum);

        // ---- P fragments: already in Z-GEMM A-layout (permutation trick)
        i32x4 P1i, P2i;
        P1i.x = pk(rnd(e[0][1] * inv), rnd(e[0][0] * inv));
        P1i.y = pk(rnd(e[0][3] * inv), rnd(e[0][2] * inv));
        P1i.z = pk(rnd(e[1][1] * inv), rnd(e[1][0] * inv));
        P1i.w = pk(rnd(e[1][3] * inv), rnd(e[1][2] * inv));
        P2i.x = pk(rnd(e[2][1] * inv), rnd(e[2][0] * inv));
        P2i.y = pk(rnd(e[2][3] * inv), rnd(e[2][2] * inv));
        P2i.z = pk(rnd(e[3][1] * inv), rnd(e[3][0] * inv));
        P2i.w = pk(rnd(e[3][3] * inv), rnd(e[3][2] * inv));
        bf16x8 P1 = __builtin_bit_cast(bf16x8, P1i);
        bf16x8 P2 = __builtin_bit_cast(bf16x8, P2i);

        // ---- Z-GEMM: Z = P @ (R_hi + R_lo), two independent chains
        f32x4 z0 = {0.0f, 0.0f, 0.0f, 0.0f};
        f32x4 z1 = {0.0f, 0.0f, 0.0f, 0.0f};
        z0 = __builtin_amdgcn_mfma_f32_16x16x32_bf16(P1, BzH0, z0, 0, 0, 0);
        z1 = __builtin_amdgcn_mfma_f32_16x16x32_bf16(P1, BzL0, z1, 0, 0, 0);
        z0 = __builtin_amdgcn_mfma_f32_16x16x32_bf16(P2, BzH1, z0, 0, 0, 0);
        z1 = __builtin_amdgcn_mfma_f32_16x16x32_bf16(P2, BzL1, z1, 0, 0, 0);

        // ---- store: lane holds Z[row 4c+r][dim i]
        const int rowbase = tile * 16;
#pragma unroll
        for (int r = 0; r < 4; ++r)
            out[(size_t)(rowbase + 4 * c + r) * CB_D + i] = z0[r] + z1[r];
    }
}

extern "C" void kernel_launch(void* const* d_in, const int* in_sizes, int n_in,
                              void* d_out, int out_size, void* d_ws, size_t ws_size,
                              hipStream_t stream) {
    const float* x   = (const float*)d_in[0];   // (64,8,32,32,16) f32
    const float* ref = (const float*)d_in[1];   // (64,16) f32
    float* out = (float*)d_out;
    char* ws = (char*)d_ws;                     // uses 8448 B

    const int nvec = in_sizes[0] / CB_D;        // 524288
    const int ntiles = nvec / 16;               // 32768

    stq_prep<<<1, 64, 0, stream>>>(ref, ws);

    const int waves = (ntiles + TILES_PW - 1) / TILES_PW;   // 16384
    const int blocks = (waves + 3) / 4;                     // 4096
    stq_main<<<blocks, 256, 0, stream>>>(x, ws, out, ntiles);
}

// Round 9
// 87.942 us; speedup vs baseline: 1.0748x; 1.0748x over previous
//
#include <hip/hip_runtime.h>
#include <math.h>

#define CB_M 64      // codewords
#define CB_D 16      // vector dim
#define HARD 5.0f
#define LOG2E 1.44269504088896340736f

typedef __attribute__((ext_vector_type(8))) short bf16x8;  // 8 bf16 = 4 VGPRs
typedef __attribute__((ext_vector_type(4))) float f32x4;
typedef __attribute__((ext_vector_type(4))) int   i32x4;

#if __has_builtin(__builtin_amdgcn_exp2f)
#define EXP2F(x) __builtin_amdgcn_exp2f(x)
#else
#define EXP2F(x) exp2f(x)
#endif

#if __has_builtin(__builtin_amdgcn_rcpf)
#define RCPF(x) __builtin_amdgcn_rcpf(x)
#else
#define RCPF(x) (1.0f / (x))
#endif

__device__ __forceinline__ ushort f2bf_rne(float f) {
    unsigned u = __float_as_uint(f);
    u += 0x7fffu + ((u >> 16) & 1u);       // RNE (prep path only)
    return (ushort)(u >> 16);
}
__device__ __forceinline__ float bf2f(ushort h) {
    return __uint_as_float(((unsigned)h) << 16);
}
// pack [bf16(a) : bf16(b)] into one dword (a = high half), TRUNCATING
__device__ __forceinline__ int pk(float a, float b) {
    return (int)__builtin_amdgcn_perm(__float_as_uint(a), __float_as_uint(b), 0x07060302u);
}
// half-ulp bump so a following truncation rounds to nearest
__device__ __forceinline__ float rnd(float a) {
    return __uint_as_float(__float_as_uint(a) + 0x8000u);
}
// truncate float to bf16 value (exact residual split)
__device__ __forceinline__ float hi_trunc(float a) {
    return __uint_as_float(__float_as_uint(a) & 0xffff0000u);
}

// Persistent fused kernel, minimized live set for 4 waves/SIMD occupancy.
//   S^T = Rperm @ Xsplit  via mfma 16x16x32 bf16 (codeword permutation
//   cw(t,m)=32(t>>1)+8(m>>2)+4(t&1)+(m&3) makes softmaxed C-layout regs
//   exactly the Z-GEMM A-operand layout).
//   hi/lo trick without A2: mfma(A1,B1) = (r_hi+r_lo).x_hi  (A1 = hi|lo)
//                           mfma(A1,B2') = r_hi.x_lo        (B2' = lo|0)
//   Z = P @ R_hi (r_lo dropped: adds <0.01 absmax, threshold 0.072)
__global__ __launch_bounds__(256, 4) void stq_main(const float* __restrict__ x,
                                                   const float* __restrict__ ref,
                                                   float* __restrict__ out,
                                                   int ntiles) {
    __shared__ __align__(16) float  cb_bias[CB_M];
    __shared__ __align__(16) ushort cb_rs_hi[CB_M][CB_D];   // (2H*log2e)*r hi
    __shared__ __align__(16) ushort cb_rs_lo[CB_M][CB_D];   // residual
    __shared__ __align__(16) ushort cb_rzT_hi[CB_D][CB_M];  // r^T (RNE bf16)

    const int tid = threadIdx.x;

    // ---- block-local codebook prep (threads 0..63) ----
    if (tid < CB_M) {
        const f32x4* rp = (const f32x4*)(ref + tid * CB_D);
        f32x4 q0 = rp[0], q1 = rp[1], q2 = rp[2], q3 = rp[3];
        float r[CB_D] = {q0.x,q0.y,q0.z,q0.w, q1.x,q1.y,q1.z,q1.w,
                         q2.x,q2.y,q2.z,q2.w, q3.x,q3.y,q3.z,q3.w};
        float r2 = 0.0f;
#pragma unroll
        for (int j = 0; j < CB_D; ++j) r2 += r[j] * r[j];
        cb_bias[tid] = -(HARD * LOG2E) * r2;
        const float s = 2.0f * HARD * LOG2E;
#pragma unroll
        for (int j = 0; j < CB_D; ++j) {
            float v = s * r[j];
            ushort h = f2bf_rne(v);
            cb_rs_hi[tid][j] = h;
            cb_rs_lo[tid][j] = f2bf_rne(v - bf2f(h));
            cb_rzT_hi[j][tid] = f2bf_rne(r[j]);
        }
    }
    __syncthreads();

    const int lane = tid & 63;
    const int wid  = tid >> 6;
    const int i = lane & 15;        // fragment n-index (vector row / Z dim)
    const int c = lane >> 4;        // k-octet quad
    const bool hiquad = (c < 2);

    // ---- resident fragments (minimal set) ----
    bf16x8 A1[4];                   // S-GEMM A: [r_hi | r_lo] across quads
    f32x4  cinit[4];                // bias splats (free via C operand)
#pragma unroll
    for (int t = 0; t < 4; ++t) {
        const int cwa = 32 * (t >> 1) + 8 * (i >> 2) + 4 * (t & 1) + (i & 3);
        const ushort* src = hiquad ? &cb_rs_hi[cwa][0] : &cb_rs_lo[cwa][0];
        A1[t] = *(const bf16x8*)(src + (c & 1) * 8);
#pragma unroll
        for (int r = 0; r < 4; ++r)
            cinit[t][r] = cb_bias[32 * (t >> 1) + 8 * c + 4 * (t & 1) + r];
    }
    bf16x8 BzH0 = *(const bf16x8*)&cb_rzT_hi[i][c * 8];
    bf16x8 BzH1 = *(const bf16x8*)&cb_rzT_hi[i][32 + c * 8];

    const int nwaves = gridDim.x * 4;       // 8192
    int tile = blockIdx.x * 4 + wid;

    // ---- prefetch first tile ----
    f32x4 nxa, nxb;
    {
        const float* xp = x + ((size_t)tile * 16 + i) * CB_D + (c & 1) * 8;
        nxa = *(const f32x4*)xp;
        nxb = *(const f32x4*)(xp + 4);
    }

#pragma unroll 1
    for (; tile < ntiles; tile += nwaves) {
        f32x4 xa = nxa, xb = nxb;
        const int nt = tile + nwaves;
        if (nt < ntiles) {
            const float* xp = x + ((size_t)nt * 16 + i) * CB_D + (c & 1) * 8;
            nxa = *(const f32x4*)xp;
            nxb = *(const f32x4*)(xp + 4);
        }

        // ---- B fragments: B1 = x_hi (trunc), B2 = residual, zeroed on c>=2
        i32x4 B1i, B2i;
        B1i.x = pk(xa.y, xa.x); B1i.y = pk(xa.w, xa.z);
        B1i.z = pk(xb.y, xb.x); B1i.w = pk(xb.w, xb.z);
        float l0 = xa.x - hi_trunc(xa.x), l1 = xa.y - hi_trunc(xa.y);
        float l2 = xa.z - hi_trunc(xa.z), l3 = xa.w - hi_trunc(xa.w);
        float l4 = xb.x - hi_trunc(xb.x), l5 = xb.y - hi_trunc(xb.y);
        float l6 = xb.z - hi_trunc(xb.z), l7 = xb.w - hi_trunc(xb.w);
        B2i.x = hiquad ? pk(rnd(l1), rnd(l0)) : 0;
        B2i.y = hiquad ? pk(rnd(l3), rnd(l2)) : 0;
        B2i.z = hiquad ? pk(rnd(l5), rnd(l4)) : 0;
        B2i.w = hiquad ? pk(rnd(l7), rnd(l6)) : 0;
        bf16x8 B1 = __builtin_bit_cast(bf16x8, B1i);
        bf16x8 B2 = __builtin_bit_cast(bf16x8, B2i);

        // ---- S^T GEMM: acc[t][r] = logit[cw 32(t>>1)+8c+4(t&1)+r][row i]
        f32x4 acc[4];
#pragma unroll
        for (int t = 0; t < 4; ++t) {
            acc[t] = __builtin_amdgcn_mfma_f32_16x16x32_bf16(A1[t], B1, cinit[t], 0, 0, 0);
            acc[t] = __builtin_amdgcn_mfma_f32_16x16x32_bf16(A1[t], B2, acc[t], 0, 0, 0);
        }

        // ---- row softmax: lanes {i,16+i,32+i,48+i} hold row i's 64 logits
        float lmax = acc[0][0];
#pragma unroll
        for (int t = 0; t < 4; ++t)
#pragma unroll
            for (int r = 0; r < 4; ++r) lmax = fmaxf(lmax, acc[t][r]);
        lmax = fmaxf(lmax, __shfl_xor(lmax, 16, 64));
        lmax = fmaxf(lmax, __shfl_xor(lmax, 32, 64));

        float lsum = 0.0f;
#pragma unroll
        for (int t = 0; t < 4; ++t)
#pragma unroll
            for (int r = 0; r < 4; ++r) {
                acc[t][r] = EXP2F(acc[t][r] - lmax);   // overwrite in place
                lsum += acc[t][r];
            }
        lsum += __shfl_xor(lsum, 16, 64);
        lsum += __shfl_xor(lsum, 32, 64);
        const float inv = RCPF(lsum);

        // ---- P fragments: already in Z-GEMM A-layout (permutation trick)
        i32x4 P1i, P2i;
        P1i.x = pk(rnd(acc[0][1] * inv), rnd(acc[0][0] * inv));
        P1i.y = pk(rnd(acc[0][3] * inv), rnd(acc[0][2] * inv));
        P1i.z = pk(rnd(acc[1][1] * inv), rnd(acc[1][0] * inv));
        P1i.w = pk(rnd(acc[1][3] * inv), rnd(acc[1][2] * inv));
        P2i.x = pk(rnd(acc[2][1] * inv), rnd(acc[2][0] * inv));
        P2i.y = pk(rnd(acc[2][3] * inv), rnd(acc[2][2] * inv));
        P2i.z = pk(rnd(acc[3][1] * inv), rnd(acc[3][0] * inv));
        P2i.w = pk(rnd(acc[3][3] * inv), rnd(acc[3][2] * inv));
        bf16x8 P1 = __builtin_bit_cast(bf16x8, P1i);
        bf16x8 P2 = __builtin_bit_cast(bf16x8, P2i);

        // ---- Z-GEMM: Z = P @ R_hi
        f32x4 z = {0.0f, 0.0f, 0.0f, 0.0f};
        z = __builtin_amdgcn_mfma_f32_16x16x32_bf16(P1, BzH0, z, 0, 0, 0);
        z = __builtin_amdgcn_mfma_f32_16x16x32_bf16(P2, BzH1, z, 0, 0, 0);

        // ---- store: lane holds Z[row 4c+r][dim i]
        const int rowbase = tile * 16;
#pragma unroll
        for (int r = 0; r < 4; ++r)
            out[(size_t)(rowbase + 4 * c + r) * CB_D + i] = z[r];
    }
}

extern "C" void kernel_launch(void* const* d_in, const int* in_sizes, int n_in,
                              void* d_out, int out_size, void* d_ws, size_t ws_size,
                              hipStream_t stream) {
    const float* x   = (const float*)d_in[0];   // (64,8,32,32,16) f32
    const float* ref = (const float*)d_in[1];   // (64,16) f32
    float* out = (float*)d_out;

    const int nvec = in_sizes[0] / CB_D;        // 524288
    const int ntiles = nvec / 16;               // 32768

    stq_main<<<2048, 256, 0, stream>>>(x, ref, out, ntiles);
}

// Round 10
// 87.210 us; speedup vs baseline: 1.0838x; 1.0084x over previous
//
#include <hip/hip_runtime.h>
#include <math.h>

#define CB_M 64      // codewords
#define CB_D 16      // vector dim
#define HARD 5.0f
#define LOG2E 1.44269504088896340736f

typedef __attribute__((ext_vector_type(8))) short bf16x8;  // 8 bf16 = 4 VGPRs
typedef __attribute__((ext_vector_type(4))) float f32x4;
typedef __attribute__((ext_vector_type(4))) int   i32x4;

#if __has_builtin(__builtin_amdgcn_exp2f)
#define EXP2F(x) __builtin_amdgcn_exp2f(x)
#else
#define EXP2F(x) exp2f(x)
#endif

#if __has_builtin(__builtin_amdgcn_rcpf)
#define RCPF(x) __builtin_amdgcn_rcpf(x)
#else
#define RCPF(x) (1.0f / (x))
#endif

__device__ __forceinline__ ushort f2bf_rne(float f) {
    unsigned u = __float_as_uint(f);
    u += 0x7fffu + ((u >> 16) & 1u);       // RNE (prep path only)
    return (ushort)(u >> 16);
}
__device__ __forceinline__ float bf2f(ushort h) {
    return __uint_as_float(((unsigned)h) << 16);
}
// pack [bf16(a) : bf16(b)] into one dword (a = high half), TRUNCATING
__device__ __forceinline__ int pk(float a, float b) {
    return (int)__builtin_amdgcn_perm(__float_as_uint(a), __float_as_uint(b), 0x07060302u);
}
// truncate float to bf16 value (exact residual split)
__device__ __forceinline__ float hi_trunc(float a) {
    return __uint_as_float(__float_as_uint(a) & 0xffff0000u);
}

// Persistent fused kernel; TWO independent tiles per iteration, stage-
// interleaved so one tile's shuffle/exp latency hides under the other's
// issue stream. Transposed-S + codeword-permutation trick (cw(t,m)=
// 32(t>>1)+8(m>>2)+4(t&1)+(m&3)): softmaxed C-layout regs are exactly the
// Z-GEMM A-operand layout. P left UNNORMALIZED; per-row 1/denom applied
// after the Z-GEMM via 4 lane-broadcast shuffles.
__global__ __launch_bounds__(256, 3) void stq_main(const float* __restrict__ x,
                                                   const float* __restrict__ ref,
                                                   float* __restrict__ out,
                                                   int ntiles) {
    __shared__ __align__(16) float  cb_bias[CB_M];
    __shared__ __align__(16) ushort cb_rs_hi[CB_M][CB_D];   // (2H*log2e)*r hi
    __shared__ __align__(16) ushort cb_rs_lo[CB_M][CB_D];   // residual
    __shared__ __align__(16) ushort cb_rzT_hi[CB_D][CB_M];  // r^T (RNE bf16)

    const int tid = threadIdx.x;

    // ---- block-local codebook prep (threads 0..63) ----
    if (tid < CB_M) {
        const f32x4* rp = (const f32x4*)(ref + tid * CB_D);
        f32x4 q0 = rp[0], q1 = rp[1], q2 = rp[2], q3 = rp[3];
        float r[CB_D] = {q0.x,q0.y,q0.z,q0.w, q1.x,q1.y,q1.z,q1.w,
                         q2.x,q2.y,q2.z,q2.w, q3.x,q3.y,q3.z,q3.w};
        float r2 = 0.0f;
#pragma unroll
        for (int j = 0; j < CB_D; ++j) r2 += r[j] * r[j];
        cb_bias[tid] = -(HARD * LOG2E) * r2;
        const float s = 2.0f * HARD * LOG2E;
#pragma unroll
        for (int j = 0; j < CB_D; ++j) {
            float v = s * r[j];
            ushort h = f2bf_rne(v);
            cb_rs_hi[tid][j] = h;
            cb_rs_lo[tid][j] = f2bf_rne(v - bf2f(h));
            cb_rzT_hi[j][tid] = f2bf_rne(r[j]);
        }
    }
    __syncthreads();

    const int lane = tid & 63;
    const int wid  = tid >> 6;
    const int i = lane & 15;        // fragment n-index (vector row / Z dim)
    const int c = lane >> 4;        // k-octet quad
    const bool hiquad = (c < 2);
    const int  bmask = hiquad ? -1 : 0;   // B2 zero mask for lo quads

    // ---- resident fragments ----
    bf16x8 A1[4];                   // S-GEMM A: [r_hi | r_lo] across quads
    f32x4  cinit[4];                // bias splats (free via C operand)
#pragma unroll
    for (int t = 0; t < 4; ++t) {
        const int cwa = 32 * (t >> 1) + 8 * (i >> 2) + 4 * (t & 1) + (i & 3);
        const ushort* src = hiquad ? &cb_rs_hi[cwa][0] : &cb_rs_lo[cwa][0];
        A1[t] = *(const bf16x8*)(src + (c & 1) * 8);
#pragma unroll
        for (int r = 0; r < 4; ++r)
            cinit[t][r] = cb_bias[32 * (t >> 1) + 8 * c + 4 * (t & 1) + r];
    }
    bf16x8 BzH0 = *(const bf16x8*)&cb_rzT_hi[i][c * 8];
    bf16x8 BzH1 = *(const bf16x8*)&cb_rzT_hi[i][32 + c * 8];

    const int nwaves = gridDim.x * 4;        // 8192
    const int npairs = ntiles >> 1;          // 16384
    int p = blockIdx.x * 4 + wid;

    // ---- prefetch first tile pair ----
    f32x4 nx0a, nx0b, nx1a, nx1b;
    {
        const float* xp = x + ((size_t)p * 32 + i) * CB_D + (c & 1) * 8;
        nx0a = *(const f32x4*)xp;
        nx0b = *(const f32x4*)(xp + 4);
        nx1a = *(const f32x4*)(xp + 16 * CB_D);
        nx1b = *(const f32x4*)(xp + 16 * CB_D + 4);
    }

#pragma unroll 1
    for (; p < npairs; p += nwaves) {
        f32x4 xa0 = nx0a, xb0 = nx0b, xa1 = nx1a, xb1 = nx1b;
        const int np_ = p + nwaves;
        if (np_ < npairs) {
            const float* xp = x + ((size_t)np_ * 32 + i) * CB_D + (c & 1) * 8;
            nx0a = *(const f32x4*)xp;
            nx0b = *(const f32x4*)(xp + 4);
            nx1a = *(const f32x4*)(xp + 16 * CB_D);
            nx1b = *(const f32x4*)(xp + 16 * CB_D + 4);
        }

        // ===== stage 1: pack B fragments, both tiles =====
        bf16x8 B1[2], B2[2];
        {
            i32x4 b1, b2;
            b1.x = pk(xa0.y, xa0.x); b1.y = pk(xa0.w, xa0.z);
            b1.z = pk(xb0.y, xb0.x); b1.w = pk(xb0.w, xb0.z);
            b2.x = pk(xa0.y - hi_trunc(xa0.y), xa0.x - hi_trunc(xa0.x)) & bmask;
            b2.y = pk(xa0.w - hi_trunc(xa0.w), xa0.z - hi_trunc(xa0.z)) & bmask;
            b2.z = pk(xb0.y - hi_trunc(xb0.y), xb0.x - hi_trunc(xb0.x)) & bmask;
            b2.w = pk(xb0.w - hi_trunc(xb0.w), xb0.z - hi_trunc(xb0.z)) & bmask;
            B1[0] = __builtin_bit_cast(bf16x8, b1);
            B2[0] = __builtin_bit_cast(bf16x8, b2);
            b1.x = pk(xa1.y, xa1.x); b1.y = pk(xa1.w, xa1.z);
            b1.z = pk(xb1.y, xb1.x); b1.w = pk(xb1.w, xb1.z);
            b2.x = pk(xa1.y - hi_trunc(xa1.y), xa1.x - hi_trunc(xa1.x)) & bmask;
            b2.y = pk(xa1.w - hi_trunc(xa1.w), xa1.z - hi_trunc(xa1.z)) & bmask;
            b2.z = pk(xb1.y - hi_trunc(xb1.y), xb1.x - hi_trunc(xb1.x)) & bmask;
            b2.w = pk(xb1.w - hi_trunc(xb1.w), xb1.z - hi_trunc(xb1.z)) & bmask;
            B1[1] = __builtin_bit_cast(bf16x8, b1);
            B2[1] = __builtin_bit_cast(bf16x8, b2);
        }

        // ===== stage 2: S^T GEMMs, both tiles =====
        f32x4 acc[2][4];
#pragma unroll
        for (int u = 0; u < 2; ++u)
#pragma unroll
            for (int t = 0; t < 4; ++t) {
                acc[u][t] = __builtin_amdgcn_mfma_f32_16x16x32_bf16(A1[t], B1[u], cinit[t], 0, 0, 0);
                acc[u][t] = __builtin_amdgcn_mfma_f32_16x16x32_bf16(A1[t], B2[u], acc[u][t], 0, 0, 0);
            }

        // ===== stage 3: row max, both tiles (shuffles interleaved) =====
        float lmax[2];
#pragma unroll
        for (int u = 0; u < 2; ++u) {
            float m01 = fmaxf(fmaxf(acc[u][0][0], acc[u][0][1]), fmaxf(acc[u][0][2], acc[u][0][3]));
            float m23 = fmaxf(fmaxf(acc[u][1][0], acc[u][1][1]), fmaxf(acc[u][1][2], acc[u][1][3]));
            float m45 = fmaxf(fmaxf(acc[u][2][0], acc[u][2][1]), fmaxf(acc[u][2][2], acc[u][2][3]));
            float m67 = fmaxf(fmaxf(acc[u][3][0], acc[u][3][1]), fmaxf(acc[u][3][2], acc[u][3][3]));
            lmax[u] = fmaxf(fmaxf(m01, m23), fmaxf(m45, m67));
        }
        float s0a = __shfl_xor(lmax[0], 16, 64);
        float s1a = __shfl_xor(lmax[1], 16, 64);
        lmax[0] = fmaxf(lmax[0], s0a);
        lmax[1] = fmaxf(lmax[1], s1a);
        s0a = __shfl_xor(lmax[0], 32, 64);
        s1a = __shfl_xor(lmax[1], 32, 64);
        lmax[0] = fmaxf(lmax[0], s0a);
        lmax[1] = fmaxf(lmax[1], s1a);

        // ===== stage 4: exp (in place) + row sum, both tiles =====
        float lsum[2];
#pragma unroll
        for (int u = 0; u < 2; ++u) {
            float s = 0.0f;
#pragma unroll
            for (int t = 0; t < 4; ++t)
#pragma unroll
                for (int r = 0; r < 4; ++r) {
                    acc[u][t][r] = EXP2F(acc[u][t][r] - lmax[u]);
                    s += acc[u][t][r];
                }
            lsum[u] = s;
        }
        s0a = __shfl_xor(lsum[0], 16, 64);
        s1a = __shfl_xor(lsum[1], 16, 64);
        lsum[0] += s0a;
        lsum[1] += s1a;
        s0a = __shfl_xor(lsum[0], 32, 64);
        s1a = __shfl_xor(lsum[1], 32, 64);
        float inv0 = RCPF(lsum[0] + s0a);
        float inv1 = RCPF(lsum[1] + s1a);

        // ===== stage 5: pack UNNORMALIZED P, Z-GEMMs, both tiles =====
        f32x4 z[2];
#pragma unroll
        for (int u = 0; u < 2; ++u) {
            i32x4 p1, p2;
            p1.x = pk(acc[u][0][1], acc[u][0][0]);
            p1.y = pk(acc[u][0][3], acc[u][0][2]);
            p1.z = pk(acc[u][1][1], acc[u][1][0]);
            p1.w = pk(acc[u][1][3], acc[u][1][2]);
            p2.x = pk(acc[u][2][1], acc[u][2][0]);
            p2.y = pk(acc[u][2][3], acc[u][2][2]);
            p2.z = pk(acc[u][3][1], acc[u][3][0]);
            p2.w = pk(acc[u][3][3], acc[u][3][2]);
            bf16x8 P1 = __builtin_bit_cast(bf16x8, p1);
            bf16x8 P2 = __builtin_bit_cast(bf16x8, p2);
            f32x4 zz = {0.0f, 0.0f, 0.0f, 0.0f};
            zz = __builtin_amdgcn_mfma_f32_16x16x32_bf16(P1, BzH0, zz, 0, 0, 0);
            zz = __builtin_amdgcn_mfma_f32_16x16x32_bf16(P2, BzH1, zz, 0, 0, 0);
            z[u] = zz;
        }

        // ===== stage 6: per-row 1/denom via lane broadcast, scale, store =====
        const int rowbase = p * 32;
#pragma unroll
        for (int r = 0; r < 4; ++r) {
            float iv0 = __shfl(inv0, 4 * c + r, 64);   // lane 4c+r holds row 4c+r
            float iv1 = __shfl(inv1, 4 * c + r, 64);
            out[(size_t)(rowbase + 4 * c + r) * CB_D + i]      = z[0][r] * iv0;
            out[(size_t)(rowbase + 16 + 4 * c + r) * CB_D + i] = z[1][r] * iv1;
        }
    }
}

extern "C" void kernel_launch(void* const* d_in, const int* in_sizes, int n_in,
                              void* d_out, int out_size, void* d_ws, size_t ws_size,
                              hipStream_t stream) {
    const float* x   = (const float*)d_in[0];   // (64,8,32,32,16) f32
    const float* ref = (const float*)d_in[1];   // (64,16) f32
    float* out = (float*)d_out;

    const int nvec = in_sizes[0] / CB_D;        // 524288
    const int ntiles = nvec / 16;               // 32768

    stq_main<<<2048, 256, 0, stream>>>(x, ref, out, ntiles);
}

// Round 11
// 86.914 us; speedup vs baseline: 1.0875x; 1.0034x over previous
//
#include <hip/hip_runtime.h>
#include <math.h>

#define CB_M 64      // codewords
#define CB_D 16      // vector dim
#define HARD 5.0f
#define LOG2E 1.44269504088896340736f

typedef __attribute__((ext_vector_type(8))) short bf16x8;  // 8 bf16 = 4 VGPRs
typedef __attribute__((ext_vector_type(4))) float f32x4;
typedef __attribute__((ext_vector_type(4))) int   i32x4;

#if __has_builtin(__builtin_amdgcn_exp2f)
#define EXP2F(x) __builtin_amdgcn_exp2f(x)
#else
#define EXP2F(x) exp2f(x)
#endif

#if __has_builtin(__builtin_amdgcn_rcpf)
#define RCPF(x) __builtin_amdgcn_rcpf(x)
#else
#define RCPF(x) (1.0f / (x))
#endif

__device__ __forceinline__ ushort f2bf_rne(float f) {
    unsigned u = __float_as_uint(f);
    u += 0x7fffu + ((u >> 16) & 1u);       // RNE (prep path only)
    return (ushort)(u >> 16);
}
__device__ __forceinline__ float bf2f(ushort h) {
    return __uint_as_float(((unsigned)h) << 16);
}
// pack [bf16(a) : bf16(b)] into one dword (a = high half), TRUNCATING
__device__ __forceinline__ int pk(float a, float b) {
    return (int)__builtin_amdgcn_perm(__float_as_uint(a), __float_as_uint(b), 0x07060302u);
}
// truncate float to bf16 value (exact residual split)
__device__ __forceinline__ float hi_trunc(float a) {
    return __uint_as_float(__float_as_uint(a) & 0xffff0000u);
}

// Persistent fused kernel, single tile per iteration, live set minimized for
// 5 waves/SIMD. Transposed-S + codeword-permutation trick (cw(t,m)=
// 32(t>>1)+8(m>>2)+4(t&1)+(m&3)): softmaxed C-layout regs are exactly the
// Z-GEMM A-operand layout. P unnormalized; per-row 1/denom applied after the
// Z-GEMM via 4 lane-broadcasts (their sum-reduce overlaps the Z MFMAs).
__global__ __launch_bounds__(256, 5) void stq_main(const float* __restrict__ x,
                                                   const float* __restrict__ ref,
                                                   float* __restrict__ out,
                                                   int ntiles) {
    __shared__ __align__(16) float  cb_bias[CB_M];
    __shared__ __align__(16) ushort cb_rs_hi[CB_M][CB_D];   // (2H*log2e)*r hi
    __shared__ __align__(16) ushort cb_rs_lo[CB_M][CB_D];   // residual
    __shared__ __align__(16) ushort cb_rzT_hi[CB_D][CB_M];  // r^T (RNE bf16)

    const int tid = threadIdx.x;

    // ---- block-local codebook prep (threads 0..63) ----
    if (tid < CB_M) {
        const f32x4* rp = (const f32x4*)(ref + tid * CB_D);
        f32x4 q0 = rp[0], q1 = rp[1], q2 = rp[2], q3 = rp[3];
        float r[CB_D] = {q0.x,q0.y,q0.z,q0.w, q1.x,q1.y,q1.z,q1.w,
                         q2.x,q2.y,q2.z,q2.w, q3.x,q3.y,q3.z,q3.w};
        float r2 = 0.0f;
#pragma unroll
        for (int j = 0; j < CB_D; ++j) r2 += r[j] * r[j];
        cb_bias[tid] = -(HARD * LOG2E) * r2;
        const float s = 2.0f * HARD * LOG2E;
#pragma unroll
        for (int j = 0; j < CB_D; ++j) {
            float v = s * r[j];
            ushort h = f2bf_rne(v);
            cb_rs_hi[tid][j] = h;
            cb_rs_lo[tid][j] = f2bf_rne(v - bf2f(h));
            cb_rzT_hi[j][tid] = f2bf_rne(r[j]);
        }
    }
    __syncthreads();

    const int lane = tid & 63;
    const int wid  = tid >> 6;
    const int i = lane & 15;        // fragment n-index (vector row / Z dim)
    const int c = lane >> 4;        // k-octet quad
    const bool hiquad = (c < 2);
    const int  bmask = hiquad ? -1 : 0;   // zero the residual on lo quads

    // ---- resident fragments ----
    bf16x8 A1[4];                   // S-GEMM A: [r_hi | r_lo] across quads
    f32x4  cinit[4];                // bias splats (free via C operand)
#pragma unroll
    for (int t = 0; t < 4; ++t) {
        const int cwa = 32 * (t >> 1) + 8 * (i >> 2) + 4 * (t & 1) + (i & 3);
        const ushort* src = hiquad ? &cb_rs_hi[cwa][0] : &cb_rs_lo[cwa][0];
        A1[t] = *(const bf16x8*)(src + (c & 1) * 8);
#pragma unroll
        for (int r = 0; r < 4; ++r)
            cinit[t][r] = cb_bias[32 * (t >> 1) + 8 * c + 4 * (t & 1) + r];
    }
    bf16x8 BzH0 = *(const bf16x8*)&cb_rzT_hi[i][c * 8];
    bf16x8 BzH1 = *(const bf16x8*)&cb_rzT_hi[i][32 + c * 8];

    const int nwaves = gridDim.x * 4;        // 8192
    int tile = blockIdx.x * 4 + wid;

    // ---- prefetch first tile ----
    f32x4 nxa, nxb;
    {
        const float* xp = x + ((size_t)tile * 16 + i) * CB_D + (c & 1) * 8;
        nxa = *(const f32x4*)xp;
        nxb = *(const f32x4*)(xp + 4);
    }

#pragma unroll 1
    for (; tile < ntiles; tile += nwaves) {
        f32x4 xa = nxa, xb = nxb;
        const int nt = tile + nwaves;
        if (nt < ntiles) {
            const float* xp = x + ((size_t)nt * 16 + i) * CB_D + (c & 1) * 8;
            nxa = *(const f32x4*)xp;
            nxb = *(const f32x4*)(xp + 4);
        }

        // ---- B fragments: B1 = x_hi (trunc), B2 = residual (zeroed on c>=2)
        i32x4 b1, b2;
        b1.x = pk(xa.y, xa.x); b1.y = pk(xa.w, xa.z);
        b1.z = pk(xb.y, xb.x); b1.w = pk(xb.w, xb.z);
        b2.x = pk(xa.y - hi_trunc(xa.y), xa.x - hi_trunc(xa.x)) & bmask;
        b2.y = pk(xa.w - hi_trunc(xa.w), xa.z - hi_trunc(xa.z)) & bmask;
        b2.z = pk(xb.y - hi_trunc(xb.y), xb.x - hi_trunc(xb.x)) & bmask;
        b2.w = pk(xb.w - hi_trunc(xb.w), xb.z - hi_trunc(xb.z)) & bmask;
        bf16x8 B1 = __builtin_bit_cast(bf16x8, b1);
        bf16x8 B2 = __builtin_bit_cast(bf16x8, b2);

        // ---- S^T GEMM: acc[t][r] = logit[cw 32(t>>1)+8c+4(t&1)+r][row i]
        f32x4 acc[4];
#pragma unroll
        for (int t = 0; t < 4; ++t) {
            acc[t] = __builtin_amdgcn_mfma_f32_16x16x32_bf16(A1[t], B1, cinit[t], 0, 0, 0);
            acc[t] = __builtin_amdgcn_mfma_f32_16x16x32_bf16(A1[t], B2, acc[t], 0, 0, 0);
        }

        // ---- row max (lanes {i,16+i,32+i,48+i} hold row i's 64 logits)
        float m01 = fmaxf(fmaxf(acc[0][0], acc[0][1]), fmaxf(acc[0][2], acc[0][3]));
        float m23 = fmaxf(fmaxf(acc[1][0], acc[1][1]), fmaxf(acc[1][2], acc[1][3]));
        float m45 = fmaxf(fmaxf(acc[2][0], acc[2][1]), fmaxf(acc[2][2], acc[2][3]));
        float m67 = fmaxf(fmaxf(acc[3][0], acc[3][1]), fmaxf(acc[3][2], acc[3][3]));
        float lmax = fmaxf(fmaxf(m01, m23), fmaxf(m45, m67));
        lmax = fmaxf(lmax, __shfl_xor(lmax, 16, 64));
        lmax = fmaxf(lmax, __shfl_xor(lmax, 32, 64));

        // ---- exp in place + row sum
        float lsum = 0.0f;
#pragma unroll
        for (int t = 0; t < 4; ++t)
#pragma unroll
            for (int r = 0; r < 4; ++r) {
                acc[t][r] = EXP2F(acc[t][r] - lmax);
                lsum += acc[t][r];
            }
        lsum += __shfl_xor(lsum, 16, 64);
        lsum += __shfl_xor(lsum, 32, 64);
        const float inv = RCPF(lsum);

        // ---- pack UNNORMALIZED P (already Z-GEMM A-layout), Z-GEMM
        i32x4 p1, p2;
        p1.x = pk(acc[0][1], acc[0][0]); p1.y = pk(acc[0][3], acc[0][2]);
        p1.z = pk(acc[1][1], acc[1][0]); p1.w = pk(acc[1][3], acc[1][2]);
        p2.x = pk(acc[2][1], acc[2][0]); p2.y = pk(acc[2][3], acc[2][2]);
        p2.z = pk(acc[3][1], acc[3][0]); p2.w = pk(acc[3][3], acc[3][2]);
        bf16x8 P1 = __builtin_bit_cast(bf16x8, p1);
        bf16x8 P2 = __builtin_bit_cast(bf16x8, p2);

        f32x4 z = {0.0f, 0.0f, 0.0f, 0.0f};
        z = __builtin_amdgcn_mfma_f32_16x16x32_bf16(P1, BzH0, z, 0, 0, 0);
        z = __builtin_amdgcn_mfma_f32_16x16x32_bf16(P2, BzH1, z, 0, 0, 0);

        // ---- per-row 1/denom via lane broadcast (overlaps Z-GEMM), store
        const int rowbase = tile * 16;
#pragma unroll
        for (int r = 0; r < 4; ++r) {
            float iv = __shfl(inv, 4 * c + r, 64);   // lane 4c+r holds row 4c+r
            out[(size_t)(rowbase + 4 * c + r) * CB_D + i] = z[r] * iv;
        }
    }
}

extern "C" void kernel_launch(void* const* d_in, const int* in_sizes, int n_in,
                              void* d_out, int out_size, void* d_ws, size_t ws_size,
                              hipStream_t stream) {
    const float* x   = (const float*)d_in[0];   // (64,8,32,32,16) f32
    const float* ref = (const float*)d_in[1];   // (64,16) f32
    float* out = (float*)d_out;

    const int nvec = in_sizes[0] / CB_D;        // 524288
    const int ntiles = nvec / 16;               // 32768

    stq_main<<<2048, 256, 0, stream>>>(x, ref, out, ntiles);
}